// Round 3
// baseline (391.905 us; speedup 1.0000x reference)
//
#include <hip/hip_runtime.h>

#define FIN 100
#define FHID 100
#define FEMB 64
#define NCLS 40

// ================= CSR build (counting sort by dst) =================

__global__ void k_zero(int* __restrict__ cnt, int n) {
    int i = blockIdx.x * blockDim.x + threadIdx.x;
    if (i < n) cnt[i] = 0;
}

__global__ void k_count(const int* __restrict__ dst, int* __restrict__ cnt, int E) {
    int e = blockIdx.x * blockDim.x + threadIdx.x;
    if (e < E) atomicAdd(&cnt[dst[e]], 1);
}

// per-256-block exclusive scan; block sums to bsum
__global__ __launch_bounds__(256) void k_scan_block(const int* __restrict__ cnt,
                                                    int* __restrict__ row,
                                                    int* __restrict__ bsum, int n) {
    __shared__ int tmp[256];
    int idx = blockIdx.x * 256 + threadIdx.x;
    int v = (idx < n) ? cnt[idx] : 0;
    tmp[threadIdx.x] = v;
    __syncthreads();
    for (int off = 1; off < 256; off <<= 1) {
        int t = (threadIdx.x >= off) ? tmp[threadIdx.x - off] : 0;
        __syncthreads();
        tmp[threadIdx.x] += t;
        __syncthreads();
    }
    if (idx < n) row[idx] = tmp[threadIdx.x] - v;  // exclusive
    if (threadIdx.x == 255) bsum[blockIdx.x] = tmp[255];
}

// single-block exclusive scan of block sums (nb <= 256)
__global__ __launch_bounds__(256) void k_scan_bsum(int* __restrict__ bsum, int nb) {
    __shared__ int tmp[256];
    int v = (threadIdx.x < nb) ? bsum[threadIdx.x] : 0;
    tmp[threadIdx.x] = v;
    __syncthreads();
    for (int off = 1; off < 256; off <<= 1) {
        int t = (threadIdx.x >= off) ? tmp[threadIdx.x - off] : 0;
        __syncthreads();
        tmp[threadIdx.x] += t;
        __syncthreads();
    }
    if (threadIdx.x < nb) bsum[threadIdx.x] = tmp[threadIdx.x] - v;
}

// rowptr += block offset; cursor = rowptr; dinv = rsqrt(deg+1); rowptr[n] = E
__global__ void k_finalize(int* __restrict__ row, const int* __restrict__ bsum,
                           int* __restrict__ cursor, const int* __restrict__ cnt,
                           float* __restrict__ dinv, int n, int E) {
    int i = blockIdx.x * blockDim.x + threadIdx.x;
    if (i < n) {
        int r = row[i] + bsum[i >> 8];
        row[i] = r;
        cursor[i] = r;
        dinv[i] = rsqrtf((float)cnt[i] + 1.0f);  // +1 self-loop
    }
    if (i == 0) row[n] = E;
}

// paired (src, norm) record: one 8B store instead of two random 4B stores
__global__ void k_scatter(const int* __restrict__ src, const int* __restrict__ dst,
                          const float* __restrict__ dinv, int* __restrict__ cursor,
                          int2* __restrict__ rec, int E) {
    int e = blockIdx.x * blockDim.x + threadIdx.x;
    if (e >= E) return;
    int d = dst[e];
    int s = src[e];
    int pos = atomicAdd(&cursor[d], 1);
    rec[pos] = make_int2(s, __float_as_int(dinv[s] * dinv[d]));
}

// ============ GEMM: one thread per row; A-row in VGPRs, W via scalar loads ============
// C[row, c..c+3] for column-groups [gbeg, gend); no LDS, inner loop is pure FMA + s_load.
template <int KIN, int KOUT, int G0, bool RELU_IN, bool BIAS>
__global__ __launch_bounds__(64) void k_gemm_rows(const float* __restrict__ A,
                                                  const float* __restrict__ W,
                                                  const float* __restrict__ bias,
                                                  float* __restrict__ C, int n) {
    const int row = blockIdx.x * 64 + threadIdx.x;
    const bool active = row < n;
    float4 a[KIN / 4];
    if (active) {
        const float4* arow = (const float4*)(A + (size_t)row * KIN);
        #pragma unroll
        for (int i = 0; i < KIN / 4; ++i) {
            float4 v = arow[i];
            if (RELU_IN) {
                v.x = fmaxf(v.x, 0.f); v.y = fmaxf(v.y, 0.f);
                v.z = fmaxf(v.z, 0.f); v.w = fmaxf(v.w, 0.f);
            }
            a[i] = v;
        }
    } else {
        #pragma unroll
        for (int i = 0; i < KIN / 4; ++i) a[i] = make_float4(0.f, 0.f, 0.f, 0.f);
    }

    const int NG = KOUT / 4;
    const int gbeg = blockIdx.y * G0;
    const int gend = (gbeg + G0 < NG) ? (gbeg + G0) : NG;
    for (int g = gbeg; g < gend; ++g) {
        const int c = __builtin_amdgcn_readfirstlane(g * 4);  // wave-uniform -> s_load W
        float4 acc;
        if (BIAS) acc = *(const float4*)&bias[c];
        else      acc = make_float4(0.f, 0.f, 0.f, 0.f);
        #pragma unroll
        for (int kk = 0; kk < KIN / 4; ++kk) {
            const float4 av = a[kk];
            const float4 w0 = *(const float4*)&W[(kk * 4 + 0) * KOUT + c];
            const float4 w1 = *(const float4*)&W[(kk * 4 + 1) * KOUT + c];
            const float4 w2 = *(const float4*)&W[(kk * 4 + 2) * KOUT + c];
            const float4 w3 = *(const float4*)&W[(kk * 4 + 3) * KOUT + c];
            acc.x = fmaf(av.x, w0.x, acc.x); acc.y = fmaf(av.x, w0.y, acc.y);
            acc.z = fmaf(av.x, w0.z, acc.z); acc.w = fmaf(av.x, w0.w, acc.w);
            acc.x = fmaf(av.y, w1.x, acc.x); acc.y = fmaf(av.y, w1.y, acc.y);
            acc.z = fmaf(av.y, w1.z, acc.z); acc.w = fmaf(av.y, w1.w, acc.w);
            acc.x = fmaf(av.z, w2.x, acc.x); acc.y = fmaf(av.z, w2.y, acc.y);
            acc.z = fmaf(av.z, w2.z, acc.z); acc.w = fmaf(av.z, w2.w, acc.w);
            acc.x = fmaf(av.w, w3.x, acc.x); acc.y = fmaf(av.w, w3.y, acc.y);
            acc.z = fmaf(av.w, w3.z, acc.z); acc.w = fmaf(av.w, w3.w, acc.w);
        }
        if (active) *(float4*)&C[(size_t)row * KOUT + c] = acc;
    }
}

// ========== CSR aggregation: out[i] = bias + h[i]*dinv[i]^2 + sum_e h[src_e]*norm_e ==========
template <int F>
__global__ __launch_bounds__(256) void k_agg_csr(const float* __restrict__ h,
                                                 const int* __restrict__ rowptr,
                                                 const int2* __restrict__ rec,
                                                 const float* __restrict__ dinv,
                                                 const float* __restrict__ bias,
                                                 float* __restrict__ out, int n) {
    const int G = F / 4;
    int gid = blockIdx.x * blockDim.x + threadIdx.x;
    if (gid >= n * G) return;
    int i = gid / G;
    int cq = gid % G;
    const float4* h4 = (const float4*)h;

    float d = dinv[i];
    float s = d * d;
    float4 hv = h4[(size_t)i * G + cq];
    float4 bv = *(const float4*)&bias[cq * 4];
    float4 acc = make_float4(fmaf(hv.x, s, bv.x), fmaf(hv.y, s, bv.y),
                             fmaf(hv.z, s, bv.z), fmaf(hv.w, s, bv.w));

    int beg = rowptr[i];
    int end = rowptr[i + 1];
    int e = beg;
    for (; e + 1 < end; e += 2) {
        int2 r0 = rec[e];
        int2 r1 = rec[e + 1];
        float n0 = __int_as_float(r0.y);
        float n1 = __int_as_float(r1.y);
        float4 v0 = h4[(size_t)r0.x * G + cq];
        float4 v1 = h4[(size_t)r1.x * G + cq];
        acc.x = fmaf(v0.x, n0, acc.x); acc.y = fmaf(v0.y, n0, acc.y);
        acc.z = fmaf(v0.z, n0, acc.z); acc.w = fmaf(v0.w, n0, acc.w);
        acc.x = fmaf(v1.x, n1, acc.x); acc.y = fmaf(v1.y, n1, acc.y);
        acc.z = fmaf(v1.z, n1, acc.z); acc.w = fmaf(v1.w, n1, acc.w);
    }
    if (e < end) {
        int2 r0 = rec[e];
        float n0 = __int_as_float(r0.y);
        float4 v0 = h4[(size_t)r0.x * G + cq];
        acc.x = fmaf(v0.x, n0, acc.x); acc.y = fmaf(v0.y, n0, acc.y);
        acc.z = fmaf(v0.z, n0, acc.z); acc.w = fmaf(v0.w, n0, acc.w);
    }
    ((float4*)out)[(size_t)i * G + cq] = acc;
}

extern "C" void kernel_launch(void* const* d_in, const int* in_sizes, int n_in,
                              void* d_out, int out_size, void* d_ws, size_t ws_size,
                              hipStream_t stream) {
    const float* x  = (const float*)d_in[0];
    const int*   ei = (const int*)d_in[1];
    const float* W1 = (const float*)d_in[2];
    const float* b1 = (const float*)d_in[3];
    const float* W2 = (const float*)d_in[4];
    const float* b2 = (const float*)d_in[5];
    const float* Wc = (const float*)d_in[6];
    const float* bc = (const float*)d_in[7];
    float* out = (float*)d_out;

    const int N = in_sizes[0] / FIN;
    const int E = in_sizes[1] / 2;
    const int* src = ei;
    const int* dst = ei + E;

    auto align = [](size_t v) { return (v + 255) & ~(size_t)255; };
    char* ws = (char*)d_ws;
    int*   deg_cnt = (int*)ws;   ws += align((size_t)N * 4);
    int*   rowptr  = (int*)ws;   ws += align((size_t)(N + 1) * 4);
    int*   cursor  = (int*)ws;   ws += align((size_t)N * 4);
    int*   bsum    = (int*)ws;   ws += align(256 * 4);
    int2*  rec     = (int2*)ws;  ws += align((size_t)E * 8);
    float* dinv    = (float*)ws; ws += align((size_t)N * 4);
    float* bufA    = (float*)ws; ws += align((size_t)N * FHID * 4);
    float* bufB    = (float*)ws; ws += align((size_t)N * FHID * 4);

    const int B = 256;
    const int nb = (N + 255) / 256;  // 196 for N=50k; k_scan_bsum requires nb<=256
    const int nrb = (N + 63) / 64;   // row-blocks for gemm

    // --- CSR build (shared by both conv layers) ---
    k_zero<<<(N + B - 1) / B, B, 0, stream>>>(deg_cnt, N);
    k_count<<<(E + B - 1) / B, B, 0, stream>>>(dst, deg_cnt, E);
    k_scan_block<<<nb, 256, 0, stream>>>(deg_cnt, rowptr, bsum, N);
    k_scan_bsum<<<1, 256, 0, stream>>>(bsum, nb);
    k_finalize<<<(N + B - 1) / B, B, 0, stream>>>(rowptr, bsum, cursor, deg_cnt, dinv, N, E);
    k_scatter<<<(E + B - 1) / B, B, 0, stream>>>(src, dst, dinv, cursor, rec, E);

    // --- layer 1: h1 = x @ W1 ; a1 = agg(h1) + b1 ---
    float* h1 = bufA;
    float* a1 = bufB;
    k_gemm_rows<FIN, FHID, 13, false, false><<<dim3(nrb, 2), 64, 0, stream>>>(x, W1, nullptr, h1, N);
    k_agg_csr<FHID><<<((size_t)N * (FHID / 4) + B - 1) / B, B, 0, stream>>>(
        h1, rowptr, rec, dinv, b1, a1, N);

    // --- layer 2: h2 = relu(a1) @ W2 ; a2 = agg(h2) + b2 ---
    float* h2 = bufA;  // h1 dead after agg-1
    k_gemm_rows<FHID, FEMB, 8, true, false><<<dim3(nrb, 2), 64, 0, stream>>>(a1, W2, nullptr, h2, N);
    float* a2 = bufB;  // a1 dead after gemm-2
    k_agg_csr<FEMB><<<((size_t)N * (FEMB / 4) + B - 1) / B, B, 0, stream>>>(
        h2, rowptr, rec, dinv, b2, a2, N);

    // --- classifier: out = relu(a2) @ Wc + bc ---
    k_gemm_rows<FEMB, NCLS, 5, true, true><<<dim3(nrb, 2), 64, 0, stream>>>(a2, Wc, bc, out, N);
}

// Round 4
// 325.923 us; speedup vs baseline: 1.2024x; 1.2024x over previous
//
#include <hip/hip_runtime.h>

#define FIN 100
#define FHID 100
#define FEMB 64
#define NCLS 40

// ================= CSR build (counting sort by dst) =================

__global__ void k_zero(int* __restrict__ cnt, int n) {
    int i = blockIdx.x * blockDim.x + threadIdx.x;
    if (i < n) cnt[i] = 0;
}

__global__ void k_count(const int* __restrict__ dst, int* __restrict__ cnt, int E) {
    int e = blockIdx.x * blockDim.x + threadIdx.x;
    if (e < E) atomicAdd(&cnt[dst[e]], 1);
}

// per-256-block exclusive scan; block sums to bsum
__global__ __launch_bounds__(256) void k_scan_block(const int* __restrict__ cnt,
                                                    int* __restrict__ row,
                                                    int* __restrict__ bsum, int n) {
    __shared__ int tmp[256];
    int idx = blockIdx.x * 256 + threadIdx.x;
    int v = (idx < n) ? cnt[idx] : 0;
    tmp[threadIdx.x] = v;
    __syncthreads();
    for (int off = 1; off < 256; off <<= 1) {
        int t = (threadIdx.x >= off) ? tmp[threadIdx.x - off] : 0;
        __syncthreads();
        tmp[threadIdx.x] += t;
        __syncthreads();
    }
    if (idx < n) row[idx] = tmp[threadIdx.x] - v;  // exclusive
    if (threadIdx.x == 255) bsum[blockIdx.x] = tmp[255];
}

// single-block exclusive scan of block sums (nb <= 256)
__global__ __launch_bounds__(256) void k_scan_bsum(int* __restrict__ bsum, int nb) {
    __shared__ int tmp[256];
    int v = (threadIdx.x < nb) ? bsum[threadIdx.x] : 0;
    tmp[threadIdx.x] = v;
    __syncthreads();
    for (int off = 1; off < 256; off <<= 1) {
        int t = (threadIdx.x >= off) ? tmp[threadIdx.x - off] : 0;
        __syncthreads();
        tmp[threadIdx.x] += t;
        __syncthreads();
    }
    if (threadIdx.x < nb) bsum[threadIdx.x] = tmp[threadIdx.x] - v;
}

// rowptr += block offset; cursor = rowptr; dinv = rsqrt(deg+1); rowptr[n] = E
__global__ void k_finalize(int* __restrict__ row, const int* __restrict__ bsum,
                           int* __restrict__ cursor, const int* __restrict__ cnt,
                           float* __restrict__ dinv, int n, int E) {
    int i = blockIdx.x * blockDim.x + threadIdx.x;
    if (i < n) {
        int r = row[i] + bsum[i >> 8];
        row[i] = r;
        cursor[i] = r;
        dinv[i] = rsqrtf((float)cnt[i] + 1.0f);  // +1 self-loop
    }
    if (i == 0) row[n] = E;
}

// 4B record: src only (norm recomputed at agg time from dinv[])
__global__ void k_scatter(const int* __restrict__ src, const int* __restrict__ dst,
                          int* __restrict__ cursor, int* __restrict__ src_sorted, int E) {
    int e = blockIdx.x * blockDim.x + threadIdx.x;
    if (e >= E) return;
    int pos = atomicAdd(&cursor[dst[e]], 1);
    src_sorted[pos] = src[e];
}

// ====== GEMM: one thread per row, A-row in VGPRs, W col-slice in LDS (broadcast reads) ======
// grid = (ceil(n/256), NSPLIT). Slice = [g0*4, (g0+gw)*4) columns; GMAX = ceil(KOUT/4/NSPLIT).
template <int KIN, int KOUT, int NSPLIT, bool RELU_IN, bool BIAS>
__global__ __launch_bounds__(256) void k_gemm_reg(const float* __restrict__ A,
                                                  const float* __restrict__ W,
                                                  const float* __restrict__ bias,
                                                  float* __restrict__ C, int n) {
    constexpr int NG = KOUT / 4;
    constexpr int GMAX = (NG + NSPLIT - 1) / NSPLIT;
    __shared__ float Ws[KIN * GMAX * 4];

    const int g0 = blockIdx.y * GMAX;
    const int gw = (g0 + GMAX <= NG) ? GMAX : (NG - g0);
    const int wcols = gw * 4;

    // cooperative stage of W[:, g0*4 .. g0*4+wcols) into LDS
    for (int idx = threadIdx.x; idx < KIN * wcols; idx += 256) {
        int k = idx / wcols;
        int cc = idx - k * wcols;
        Ws[k * (GMAX * 4) + cc] = W[k * KOUT + g0 * 4 + cc];
    }

    const int row = blockIdx.x * 256 + threadIdx.x;
    const bool active = row < n;
    float4 a[KIN / 4];
    if (active) {
        const float4* arow = (const float4*)(A + (size_t)row * KIN);
        #pragma unroll
        for (int i = 0; i < KIN / 4; ++i) {
            float4 v = arow[i];
            if (RELU_IN) {
                v.x = fmaxf(v.x, 0.f); v.y = fmaxf(v.y, 0.f);
                v.z = fmaxf(v.z, 0.f); v.w = fmaxf(v.w, 0.f);
            }
            a[i] = v;
        }
    }
    __syncthreads();
    if (!active) return;

    for (int g = 0; g < gw; ++g) {
        float4 acc;
        if (BIAS) acc = *(const float4*)&bias[(g0 + g) * 4];
        else      acc = make_float4(0.f, 0.f, 0.f, 0.f);
        const float* wbase = &Ws[g * 4];
        #pragma unroll
        for (int kq = 0; kq < KIN / 4; ++kq) {
            const float4 av = a[kq];
            const float4 w0 = *(const float4*)&wbase[(kq * 4 + 0) * (GMAX * 4)];
            const float4 w1 = *(const float4*)&wbase[(kq * 4 + 1) * (GMAX * 4)];
            const float4 w2 = *(const float4*)&wbase[(kq * 4 + 2) * (GMAX * 4)];
            const float4 w3 = *(const float4*)&wbase[(kq * 4 + 3) * (GMAX * 4)];
            acc.x = fmaf(av.x, w0.x, acc.x); acc.y = fmaf(av.x, w0.y, acc.y);
            acc.z = fmaf(av.x, w0.z, acc.z); acc.w = fmaf(av.x, w0.w, acc.w);
            acc.x = fmaf(av.y, w1.x, acc.x); acc.y = fmaf(av.y, w1.y, acc.y);
            acc.z = fmaf(av.y, w1.z, acc.z); acc.w = fmaf(av.y, w1.w, acc.w);
            acc.x = fmaf(av.z, w2.x, acc.x); acc.y = fmaf(av.z, w2.y, acc.y);
            acc.z = fmaf(av.z, w2.z, acc.z); acc.w = fmaf(av.z, w2.w, acc.w);
            acc.x = fmaf(av.w, w3.x, acc.x); acc.y = fmaf(av.w, w3.y, acc.y);
            acc.z = fmaf(av.w, w3.z, acc.z); acc.w = fmaf(av.w, w3.w, acc.w);
        }
        *(float4*)&C[(size_t)row * KOUT + (g0 + g) * 4] = acc;
    }
}

// ===== CSR aggregation: out_i = b + d_i*(d_i*h_i + sum_e dinv[s_e]*h[s_e]) =====
template <int F>
__global__ __launch_bounds__(256) void k_agg_csr(const float* __restrict__ h,
                                                 const int* __restrict__ rowptr,
                                                 const int* __restrict__ src_sorted,
                                                 const float* __restrict__ dinv,
                                                 const float* __restrict__ bias,
                                                 float* __restrict__ out, int n) {
    const int G = F / 4;
    int gid = blockIdx.x * blockDim.x + threadIdx.x;
    if (gid >= n * G) return;
    int i = gid / G;
    int cq = gid % G;
    const float4* h4 = (const float4*)h;

    float4 acc = make_float4(0.f, 0.f, 0.f, 0.f);
    int beg = rowptr[i];
    int end = rowptr[i + 1];
    int e = beg;
    for (; e + 1 < end; e += 2) {
        int s0 = src_sorted[e];
        int s1 = src_sorted[e + 1];
        float n0 = dinv[s0];
        float n1 = dinv[s1];
        float4 v0 = h4[(size_t)s0 * G + cq];
        float4 v1 = h4[(size_t)s1 * G + cq];
        acc.x = fmaf(v0.x, n0, acc.x); acc.y = fmaf(v0.y, n0, acc.y);
        acc.z = fmaf(v0.z, n0, acc.z); acc.w = fmaf(v0.w, n0, acc.w);
        acc.x = fmaf(v1.x, n1, acc.x); acc.y = fmaf(v1.y, n1, acc.y);
        acc.z = fmaf(v1.z, n1, acc.z); acc.w = fmaf(v1.w, n1, acc.w);
    }
    if (e < end) {
        int s0 = src_sorted[e];
        float n0 = dinv[s0];
        float4 v0 = h4[(size_t)s0 * G + cq];
        acc.x = fmaf(v0.x, n0, acc.x); acc.y = fmaf(v0.y, n0, acc.y);
        acc.z = fmaf(v0.z, n0, acc.z); acc.w = fmaf(v0.w, n0, acc.w);
    }

    float d = dinv[i];
    float4 hv = h4[(size_t)i * G + cq];
    float4 bv = *(const float4*)&bias[cq * 4];
    float4 o;
    o.x = fmaf(d, fmaf(d, hv.x, acc.x), bv.x);
    o.y = fmaf(d, fmaf(d, hv.y, acc.y), bv.y);
    o.z = fmaf(d, fmaf(d, hv.z, acc.z), bv.z);
    o.w = fmaf(d, fmaf(d, hv.w, acc.w), bv.w);
    ((float4*)out)[(size_t)i * G + cq] = o;
}

extern "C" void kernel_launch(void* const* d_in, const int* in_sizes, int n_in,
                              void* d_out, int out_size, void* d_ws, size_t ws_size,
                              hipStream_t stream) {
    const float* x  = (const float*)d_in[0];
    const int*   ei = (const int*)d_in[1];
    const float* W1 = (const float*)d_in[2];
    const float* b1 = (const float*)d_in[3];
    const float* W2 = (const float*)d_in[4];
    const float* b2 = (const float*)d_in[5];
    const float* Wc = (const float*)d_in[6];
    const float* bc = (const float*)d_in[7];
    float* out = (float*)d_out;

    const int N = in_sizes[0] / FIN;
    const int E = in_sizes[1] / 2;
    const int* src = ei;
    const int* dst = ei + E;

    auto align = [](size_t v) { return (v + 255) & ~(size_t)255; };
    char* ws = (char*)d_ws;
    int*   deg_cnt    = (int*)ws;   ws += align((size_t)N * 4);
    int*   rowptr     = (int*)ws;   ws += align((size_t)(N + 1) * 4);
    int*   cursor     = (int*)ws;   ws += align((size_t)N * 4);
    int*   bsum       = (int*)ws;   ws += align(256 * 4);
    int*   src_sorted = (int*)ws;   ws += align((size_t)E * 4);
    float* dinv       = (float*)ws; ws += align((size_t)N * 4);
    float* bufA       = (float*)ws; ws += align((size_t)N * FHID * 4);
    float* bufB       = (float*)ws; ws += align((size_t)N * FHID * 4);

    const int B = 256;
    const int nb = (N + 255) / 256;   // 196 for N=50k; k_scan_bsum requires nb<=256
    const int ngb = (N + 255) / 256;  // gemm row-blocks

    // --- CSR build (shared by both conv layers) ---
    k_zero<<<(N + B - 1) / B, B, 0, stream>>>(deg_cnt, N);
    k_count<<<(E + B - 1) / B, B, 0, stream>>>(dst, deg_cnt, E);
    k_scan_block<<<nb, 256, 0, stream>>>(deg_cnt, rowptr, bsum, N);
    k_scan_bsum<<<1, 256, 0, stream>>>(bsum, nb);
    k_finalize<<<(N + B - 1) / B, B, 0, stream>>>(rowptr, bsum, cursor, deg_cnt, dinv, N, E);
    k_scatter<<<(E + B - 1) / B, B, 0, stream>>>(src, dst, cursor, src_sorted, E);

    // --- layer 1: h1 = x @ W1 ; a1 = agg(h1) + b1 ---
    float* h1 = bufA;
    float* a1 = bufB;
    k_gemm_reg<FIN, FHID, 2, false, false><<<dim3(ngb, 2), 256, 0, stream>>>(x, W1, nullptr, h1, N);
    k_agg_csr<FHID><<<((size_t)N * (FHID / 4) + B - 1) / B, B, 0, stream>>>(
        h1, rowptr, src_sorted, dinv, b1, a1, N);

    // --- layer 2: h2 = relu(a1) @ W2 ; a2 = agg(h2) + b2 ---
    float* h2 = bufA;  // h1 dead after agg-1
    k_gemm_reg<FHID, FEMB, 2, true, false><<<dim3(ngb, 2), 256, 0, stream>>>(a1, W2, nullptr, h2, N);
    float* a2 = bufB;  // a1 dead after gemm-2
    k_agg_csr<FEMB><<<((size_t)N * (FEMB / 4) + B - 1) / B, B, 0, stream>>>(
        h2, rowptr, src_sorted, dinv, b2, a2, N);

    // --- classifier: out = relu(a2) @ Wc + bc ---
    k_gemm_reg<FEMB, NCLS, 2, true, true><<<dim3(ngb, 2), 256, 0, stream>>>(a2, Wc, bc, out, N);
}